// Round 17
// baseline (255.063 us; speedup 1.0000x reference)
//
#include <hip/hip_runtime.h>
#include <hip/hip_bf16.h>
#include <math.h>

#define BLOCK 256
#define IMG 512
#define NBLOCKS 3072            // 96 planes * 8 col-tiles * 4 row-chunks
#define NACC 128
#define N_TOTAL 25165824.0f

typedef float f32x4 __attribute__((ext_vector_type(4)));
typedef short s16x8 __attribute__((ext_vector_type(8)));
typedef short s16x4 __attribute__((ext_vector_type(4)));

struct WB { unsigned short b[11]; float c2; float k1; float k2; };
union FR  { unsigned int u[4]; s16x8 s; };
union FR2 { unsigned int u[2]; s16x4 s; };

// K=16 bf16 MFMA (verified correct R4..R16: passed, absmax 0.0)
#if __has_builtin(__builtin_amdgcn_mfma_f32_16x16x16bf16_1k)
#define MFMA16(A,B,C) __builtin_amdgcn_mfma_f32_16x16x16bf16_1k((A),(B),(C),0,0,0)
#else
__device__ __forceinline__ f32x4 mfma16_asm(s16x4 a, s16x4 b, f32x4 c) {
    f32x4 d;
    asm("v_mfma_f32_16x16x16_bf16 %0, %1, %2, %3" : "=v"(d) : "v"(a), "v"(b), "v"(c));
    return d;
}
#define MFMA16(A,B,C) mfma16_asm((A),(B),(C))
#endif

__device__ __forceinline__ unsigned int pk2(float a, float b) {
    union { __hip_bfloat162 h; unsigned int u; } cv;
    cv.h = __float22bfloat162_rn(make_float2(a, b));
    return cv.u;
}

// direct global->LDS DMA, 16B per lane; dest = wave-uniform base + lane*16
__device__ __forceinline__ void ldsload16(const float* g, float* l) {
    __builtin_amdgcn_global_load_lds(
        (const __attribute__((address_space(1))) unsigned int*)g,
        (__attribute__((address_space(3))) unsigned int*)l, 16, 0, 0);
}

// counted-vmcnt barrier (T4): loads for step s+2 stay in flight (vmcnt(4)),
// lgkmcnt(0) retires this wave's ds_reads before others' DMA can overwrite.
#define WAITSYNC(N) do { \
    asm volatile("s_waitcnt vmcnt(" #N ") lgkmcnt(0)" ::: "memory"); \
    __builtin_amdgcn_s_barrier(); \
    asm volatile("" ::: "memory"); \
} while (0)

// ---- staging geometry ----
// Per step-buffer: 320 slots (16 rows x 20 chunks of 16B) per input, x then y.
// Slot s=(r*20+p) holds image chunk c = (p+7r)%20  [rotation spreads banks on
// the strided H reads; read position p = (c+13r)%20]. DMA dest is linear
// slot*16B (required); the rotation lives in the per-lane GLOBAL source addr.
// rowok needed only at steps 0 (top halo) and 8 (bottom halo).
#define ROK(S, r) (((S) != 0 || R0 > 0 || (r) >= 5) && \
                   ((S) != 8 || R0 != 384 || (r) < 5))
#define SRCA(S) ((colokA && ROK(S, rA)) ? (baseXA + (S) * 8192) : zp)
#define SRCYA(S) ((colokA && ROK(S, rA)) ? (baseYA + (S) * 8192) : zp)
#define SRCB(S) ((colokB && ROK(S, rB)) ? (baseXB + (S) * 8192) : zp)
#define SRCYB(S) ((colokB && ROK(S, rB)) ? (baseYB + (S) * 8192) : zp)

#define ISSUE(S) do {                                                        \
    float* dx_ = &s_buf[(S) % 3][0][w * 320];                                \
    float* dy_ = &s_buf[(S) % 3][1][w * 320];                                \
    ldsload16(SRCA(S), dx_);                                                 \
    ldsload16(SRCYA(S), dy_);                                                \
    if (lane < 16) {                                                         \
        ldsload16(SRCB(S), dx_ + 256);                                       \
        ldsload16(SRCYB(S), dy_ + 256);                                      \
    }                                                                        \
} while (0)

// H: read raw f32 x,y (4x ds_read_b128), build 4 bf16 A-fragments in-reg
// (x, y, x^2+y^2, x*y — conv is linear so sum-matrix works, verified R5+),
// 4x MFMA K=32 vs band weights bw -> pack D to bf16 fragments.
#define H_PHASE(CUR, S) do {                                                 \
    const f32x4 x0_ = *(const f32x4*)&s_buf[(S) % 3][0][offX1];              \
    const f32x4 x1_ = *(const f32x4*)&s_buf[(S) % 3][0][offX2];              \
    const f32x4 y0_ = *(const f32x4*)&s_buf[(S) % 3][1][offX1];              \
    const f32x4 y1_ = *(const f32x4*)&s_buf[(S) % 3][1][offX2];              \
    FR a0_, a1_, a2_, a3_;                                                   \
    a0_.u[0] = pk2(x0_[0], x0_[1]); a0_.u[1] = pk2(x0_[2], x0_[3]);          \
    a0_.u[2] = pk2(x1_[0], x1_[1]); a0_.u[3] = pk2(x1_[2], x1_[3]);          \
    a1_.u[0] = pk2(y0_[0], y0_[1]); a1_.u[1] = pk2(y0_[2], y0_[3]);          \
    a1_.u[2] = pk2(y1_[0], y1_[1]); a1_.u[3] = pk2(y1_[2], y1_[3]);          \
    a2_.u[0] = pk2(x0_[0]*x0_[0] + y0_[0]*y0_[0], x0_[1]*x0_[1] + y0_[1]*y0_[1]); \
    a2_.u[1] = pk2(x0_[2]*x0_[2] + y0_[2]*y0_[2], x0_[3]*x0_[3] + y0_[3]*y0_[3]); \
    a2_.u[2] = pk2(x1_[0]*x1_[0] + y1_[0]*y1_[0], x1_[1]*x1_[1] + y1_[1]*y1_[1]); \
    a2_.u[3] = pk2(x1_[2]*x1_[2] + y1_[2]*y1_[2], x1_[3]*x1_[3] + y1_[3]*y1_[3]); \
    a3_.u[0] = pk2(x0_[0]*y0_[0], x0_[1]*y0_[1]);                            \
    a3_.u[1] = pk2(x0_[2]*y0_[2], x0_[3]*y0_[3]);                            \
    a3_.u[2] = pk2(x1_[0]*y1_[0], x1_[1]*y1_[1]);                            \
    a3_.u[3] = pk2(x1_[2]*y1_[2], x1_[3]*y1_[3]);                            \
    f32x4 d0_ = __builtin_amdgcn_mfma_f32_16x16x32_bf16(a0_.s, bw.s, z,0,0,0);\
    f32x4 d1_ = __builtin_amdgcn_mfma_f32_16x16x32_bf16(a1_.s, bw.s, z,0,0,0);\
    f32x4 d2_ = __builtin_amdgcn_mfma_f32_16x16x32_bf16(a2_.s, bw.s, z,0,0,0);\
    f32x4 d3_ = __builtin_amdgcn_mfma_f32_16x16x32_bf16(a3_.s, bw.s, z,0,0,0);\
    CUR[0].u[0]=pk2(d0_[0],d0_[1]); CUR[0].u[1]=pk2(d0_[2],d0_[3]);          \
    CUR[1].u[0]=pk2(d1_[0],d1_[1]); CUR[1].u[1]=pk2(d1_[2],d1_[3]);          \
    CUR[2].u[0]=pk2(d2_[0],d2_[1]); CUR[2].u[1]=pk2(d2_[2],d2_[3]);          \
    CUR[3].u[0]=pk2(d3_[0],d3_[1]); CUR[3].u[1]=pk2(d3_[2],d3_[3]);          \
} while (0)

// V: register-only hand-off (H D-fragments are V's B-fragments), 8x MFMA K=16
#define V_PHASE(CUR, PRV) do {                                               \
    f32x4 c0_ = MFMA16(awhi.s, CUR[0].s, z);                                 \
    f32x4 c1_ = MFMA16(awhi.s, CUR[1].s, z);                                 \
    f32x4 c2_ = MFMA16(awhi.s, CUR[2].s, z);                                 \
    f32x4 c3_ = MFMA16(awhi.s, CUR[3].s, z);                                 \
    c0_ = MFMA16(awlo.s, PRV[0].s, c0_);                                     \
    c1_ = MFMA16(awlo.s, PRV[1].s, c1_);                                     \
    c2_ = MFMA16(awlo.s, PRV[2].s, c2_);                                     \
    c3_ = MFMA16(awlo.s, PRV[3].s, c3_);                                     \
    _Pragma("unroll")                                                        \
    for (int i = 0; i < 4; ++i) {                                            \
        const float u1   = c0_[i];                                           \
        const float u2   = c1_[i];                                           \
        const float m11  = u1 * u1;                                          \
        const float m22  = u2 * u2;                                          \
        const float m12  = u1 * u2;                                          \
        const float esum = c2_[i] * c2;      /* e11+e22 */                   \
        const float e12  = c3_[i] * c2;                                      \
        const float A_ = fmaf(2.f, m12, K1);                                 \
        const float B_ = fmaf(2.f, e12 - m12, K2);                           \
        const float C_ = m11 + m22 + K1;                                     \
        const float D_ = esum - (m11 + m22) + K2;                            \
        lsum = fmaf(A_ * B_, __builtin_amdgcn_rcpf(C_ * D_), lsum);          \
    }                                                                        \
} while (0)

__global__ __launch_bounds__(BLOCK, 5)
void ssim_tiled(const float* __restrict__ pred,
                const float* __restrict__ targ,
                float* __restrict__ accum, WB wb) {
    // triple-buffered raw f32 staging: 3 bufs x {x,y} x 1280 floats = 30,720 B
    __shared__ __align__(16) float s_buf[3][2][1280];

    const int tid = threadIdx.x;
    const int bx    = blockIdx.x;
    const int plane = bx >> 5;
    const int rem   = bx & 31;
    const int tx    = rem >> 2;
    const int ry    = rem & 3;
    const int C0    = tx * 64;
    const int R0    = ry * 128;

    const float* P = pred + (size_t)plane * (IMG * IMG);
    const float* T = targ + (size_t)plane * (IMG * IMG);
    const float* zp = accum + NACC;      // 16B zero page (memset by host code)

    const int w    = tid >> 6;
    const int lane = tid & 63;
    const int l15  = lane & 15;
    const int quad = lane >> 4;

    // ---- staging (write) side: lane -> slot -> rotated global chunk ----
    const int sA = w * 80 + lane;
    const int rA = sA / 20, pA = sA % 20;
    const int cA = (pA + 7 * rA) % 20;
    const int colA = C0 - 8 + 4 * cA;
    const bool colokA = (colA >= 0) && (colA + 4 <= IMG);
    const int sB = w * 80 + 64 + lane;   // meaningful for lane<16
    const int rB = sB / 20, pB = sB % 20;
    const int cB = (pB + 7 * rB) % 20;
    const int colB = C0 - 8 + 4 * cB;
    const bool colokB = (colB >= 0) && (colB + 4 <= IMG);

    // step-0 source bases (row R0-5+r); may be OOB-by-address for bad rows —
    // never dereferenced (SRC* selects zp). step s adds s*8192 floats.
    const float* baseXA = P + ((size_t)(R0 - 5 + rA) << 9) + colA;
    const float* baseYA = T + ((size_t)(R0 - 5 + rA) << 9) + colA;
    const float* baseXB = P + ((size_t)(R0 - 5 + rB) << 9) + colB;
    const float* baseYB = T + ((size_t)(R0 - 5 + rB) << 9) + colB;

    // ---- H (read) side: chunks c1,c1+1 of row l15, rotated positions ----
    const int c1 = 4 * w + 2 * quad;
    const int p1 = (c1 + 13 * l15) % 20;
    const int p2 = (c1 + 1 + 13 * l15) % 20;
    const int offX1 = (l15 * 20 + p1) * 4;
    const int offX2 = (l15 * 20 + p2) * 4;

    const float c2 = wb.c2, K1 = wb.k1, K2 = wb.k2;
    const f32x4 z = {0.f, 0.f, 0.f, 0.f};
    float lsum = 0.f;

    // ---- prologue: 2 step-tiles of DMA in flight, weights under latency ----
    ISSUE(0);
    ISSUE(1);

    // weight fragments in registers (verified R4..R16):
    // T[i] = ((i&31)<=10) ? b[i&31] : 0 ; pairT[i] = (T[i], T[(i+1)&63]).
    // bw   (H, K=32 B-op): word t = pairT[(8*quad - l15 - 3 + 2t)&63]
    // awlo (V, K=16 A-op): word t = pairT[(4*quad - l15      + 2t)&63]
    // awhi (V, K=16 A-op): word t = pairT[(4*quad - l15 + 16 + 2t)&63]
    FR bw; FR2 awlo, awhi;
    {
        const int ti = lane & 31;
        int tv = 0;
#pragma unroll
        for (int k = 0; k < 11; ++k) tv = (ti == k) ? (int)wb.b[k] : tv;
        const int tnext = __shfl(tv, (lane + 1) & 63);
        const int pairT = (tv & 0xffff) | (tnext << 16);
        const int base_b = 8 * quad - l15 - 3;
        const int baseL  = 4 * quad - l15;
        const int baseH  = 4 * quad - l15 + 16;
#pragma unroll
        for (int t = 0; t < 4; ++t)
            bw.u[t] = (unsigned int)__shfl(pairT, (base_b + 2 * t) & 63);
#pragma unroll
        for (int t = 0; t < 2; ++t) {
            awlo.u[t] = (unsigned int)__shfl(pairT, (baseL + 2 * t) & 63);
            awhi.u[t] = (unsigned int)__shfl(pairT, (baseH + 2 * t) & 63);
        }
    }

    WAITSYNC(4);                   // step-0 DMA landed (step-1 still flying)

    FR2 vbE[4], vbO[4];            // H fragments, even/odd steps

    // STEP(s): issue DMA(s+2) -> buf[(s+2)%3] (last read at s-1, safe);
    // H reads buf[s%3]; end: vmcnt(4) keeps DMA(s+2) flying, drains DMA(s+1).
    ISSUE(2);  H_PHASE(vbE, 0);                        WAITSYNC(4);
    ISSUE(3);  H_PHASE(vbO, 1);  V_PHASE(vbO, vbE);    WAITSYNC(4);
    ISSUE(4);  H_PHASE(vbE, 2);  V_PHASE(vbE, vbO);    WAITSYNC(4);
    ISSUE(5);  H_PHASE(vbO, 3);  V_PHASE(vbO, vbE);    WAITSYNC(4);
    ISSUE(6);  H_PHASE(vbE, 4);  V_PHASE(vbE, vbO);    WAITSYNC(4);
    ISSUE(7);  H_PHASE(vbO, 5);  V_PHASE(vbO, vbE);    WAITSYNC(4);
    ISSUE(8);  H_PHASE(vbE, 6);  V_PHASE(vbE, vbO);    WAITSYNC(4);
               H_PHASE(vbO, 7);  V_PHASE(vbO, vbE);    WAITSYNC(0);
               H_PHASE(vbE, 8);  V_PHASE(vbE, vbO);

#pragma unroll
    for (int off = 32; off > 0; off >>= 1) lsum += __shfl_down(lsum, off, 64);
    if (lane == 0) atomicAdd(&accum[(bx * 4 + w) & (NACC - 1)], lsum);
}

__global__ void ssim_finalize(const float* __restrict__ accum, float* __restrict__ out) {
    const int l = threadIdx.x;
    float v = accum[l] + accum[l + 64];
#pragma unroll
    for (int off = 32; off > 0; off >>= 1) v += __shfl_down(v, off, 64);
    if (l == 0) out[0] = 1.0f - v * (1.0f / N_TOTAL);
}

extern "C" void kernel_launch(void* const* d_in, const int* in_sizes, int n_in,
                              void* d_out, int out_size, void* d_ws, size_t ws_size,
                              hipStream_t stream) {
    const float* pred = (const float*)d_in[0];
    const float* targ = (const float*)d_in[1];
    float* out = (float*)d_out;
    float* ws  = (float*)d_ws;

    WB wb;
    {
        double gg[11], sum = 0.0;
        for (int k = 0; k < 11; ++k) {
            const double d = (double)(k - 5);
            gg[k] = exp(-d * d / 4.5);
            sum += gg[k];
        }
        double sbf = 0.0;
        for (int k = 0; k < 11; ++k) {
            union { float f; unsigned int u; } cv;
            cv.f = (float)(gg[k] / sum);
            const unsigned int r = (cv.u + 0x7fffu + ((cv.u >> 16) & 1u)) >> 16;
            wb.b[k] = (unsigned short)r;
            union { float f; unsigned int u; } bk;
            bk.u = r << 16;
            sbf += (double)bk.f;
        }
        const double s2 = sbf * sbf;       // acc = s2 * true value
        wb.c2 = (float)s2;
        wb.k1 = (float)(0.0001 * s2 * s2); // C1 in acc^2 units
        wb.k2 = (float)(0.0009 * s2 * s2); // C2 in acc^2 units
    }

    // accum[0..NACC) = partial sums; accum[NACC..NACC+4) = DMA zero page
    hipMemsetAsync(ws, 0, (NACC + 4) * sizeof(float), stream);
    ssim_tiled<<<NBLOCKS, BLOCK, 0, stream>>>(pred, targ, ws, wb);
    ssim_finalize<<<1, 64, 0, stream>>>(ws, out);
}

// Round 19
// 226.125 us; speedup vs baseline: 1.1280x; 1.1280x over previous
//
#include <hip/hip_runtime.h>
#include <hip/hip_bf16.h>
#include <math.h>

#define BLOCK 256
#define IMG 512
#define NBLOCKS 3072            // 96 planes * 8 col-tiles * 4 row-chunks
#define NACC 128
#define N_TOTAL 25165824.0f

typedef float f32x4 __attribute__((ext_vector_type(4)));
typedef short s16x8 __attribute__((ext_vector_type(8)));
typedef short s16x4 __attribute__((ext_vector_type(4)));

struct WB { unsigned short b[11]; float c2; float k1; float k2; };
union FR  { unsigned int u[4]; s16x8 s; };
union FR2 { unsigned int u[2]; s16x4 s; };

// K=16 bf16 MFMA (verified correct R4..R17: passed, absmax 0.0)
#if __has_builtin(__builtin_amdgcn_mfma_f32_16x16x16bf16_1k)
#define MFMA16(A,B,C) __builtin_amdgcn_mfma_f32_16x16x16bf16_1k((A),(B),(C),0,0,0)
#else
__device__ __forceinline__ f32x4 mfma16_asm(s16x4 a, s16x4 b, f32x4 c) {
    f32x4 d;
    asm("v_mfma_f32_16x16x16_bf16 %0, %1, %2, %3" : "=v"(d) : "v"(a), "v"(b), "v"(c));
    return d;
}
#define MFMA16(A,B,C) mfma16_asm((A),(B),(C))
#endif

__device__ __forceinline__ unsigned int pk2(float a, float b) {
    union { __hip_bfloat162 h; unsigned int u; } cv;
    cv.h = __float22bfloat162_rn(make_float2(a, b));
    return cv.u;
}

// direct global->LDS DMA, 16B per lane; dest = wave-uniform base + lane*16
__device__ __forceinline__ void ldsload16(const float* g, float* l) {
    __builtin_amdgcn_global_load_lds(
        (const __attribute__((address_space(1))) unsigned int*)g,
        (__attribute__((address_space(3))) unsigned int*)l, 16, 0, 0);
}

// counted-vmcnt barrier (T4): loads for step s+2 stay in flight (vmcnt(4)),
// lgkmcnt(0) retires this wave's ds_reads before others' DMA can overwrite.
#define WAITSYNC(N) do { \
    asm volatile("s_waitcnt vmcnt(" #N ") lgkmcnt(0)" ::: "memory"); \
    __builtin_amdgcn_s_barrier(); \
    asm volatile("" ::: "memory"); \
} while (0)

// ---- staging geometry ----
// Per step-buffer: 320 slots (16 rows x 20 chunks of 16B) per input, x then y.
// Slot s=(r*20+p) holds image chunk c = (p+7r)%20  [rotation spreads banks on
// the strided H reads; read position p = (c+13r)%20]. DMA dest is linear
// slot*16B (required); the rotation lives in the per-lane GLOBAL source addr.
// rowok needed only at steps 0 (top halo) and 8 (bottom halo).
#define ROK(S, r) (((S) != 0 || R0 > 0 || (r) >= 5) && \
                   ((S) != 8 || R0 != 384 || (r) < 5))
#define SRCA(S) ((colokA && ROK(S, rA)) ? (baseXA + (S) * 8192) : zp)
#define SRCYA(S) ((colokA && ROK(S, rA)) ? (baseYA + (S) * 8192) : zp)
#define SRCB(S) ((colokB && ROK(S, rB)) ? (baseXB + (S) * 8192) : zp)
#define SRCYB(S) ((colokB && ROK(S, rB)) ? (baseYB + (S) * 8192) : zp)

#define ISSUE(S) do {                                                        \
    float* dx_ = &s_buf[(S) % 3][0][w * 320];                                \
    float* dy_ = &s_buf[(S) % 3][1][w * 320];                                \
    ldsload16(SRCA(S), dx_);                                                 \
    ldsload16(SRCYA(S), dy_);                                                \
    if (lane < 16) {                                                         \
        ldsload16(SRCB(S), dx_ + 256);                                       \
        ldsload16(SRCYB(S), dy_ + 256);                                      \
    }                                                                        \
} while (0)

// H: read raw f32 x,y (4x ds_read_b128), build 4 bf16 A-fragments in-reg
// (x, y, x^2+y^2, x*y — conv is linear so sum-matrix works, verified R5+),
// 4x MFMA K=32 vs band weights bw -> pack D to bf16 fragments.
#define H_PHASE(CUR, S) do {                                                 \
    const f32x4 x0_ = *(const f32x4*)&s_buf[(S) % 3][0][offX1];              \
    const f32x4 x1_ = *(const f32x4*)&s_buf[(S) % 3][0][offX2];              \
    const f32x4 y0_ = *(const f32x4*)&s_buf[(S) % 3][1][offX1];              \
    const f32x4 y1_ = *(const f32x4*)&s_buf[(S) % 3][1][offX2];              \
    FR a0_, a1_, a2_, a3_;                                                   \
    a0_.u[0] = pk2(x0_[0], x0_[1]); a0_.u[1] = pk2(x0_[2], x0_[3]);          \
    a0_.u[2] = pk2(x1_[0], x1_[1]); a0_.u[3] = pk2(x1_[2], x1_[3]);          \
    a1_.u[0] = pk2(y0_[0], y0_[1]); a1_.u[1] = pk2(y0_[2], y0_[3]);          \
    a1_.u[2] = pk2(y1_[0], y1_[1]); a1_.u[3] = pk2(y1_[2], y1_[3]);          \
    a2_.u[0] = pk2(x0_[0]*x0_[0] + y0_[0]*y0_[0], x0_[1]*x0_[1] + y0_[1]*y0_[1]); \
    a2_.u[1] = pk2(x0_[2]*x0_[2] + y0_[2]*y0_[2], x0_[3]*x0_[3] + y0_[3]*y0_[3]); \
    a2_.u[2] = pk2(x1_[0]*x1_[0] + y1_[0]*y1_[0], x1_[1]*x1_[1] + y1_[1]*y1_[1]); \
    a2_.u[3] = pk2(x1_[2]*x1_[2] + y1_[2]*y1_[2], x1_[3]*x1_[3] + y1_[3]*y1_[3]); \
    a3_.u[0] = pk2(x0_[0]*y0_[0], x0_[1]*y0_[1]);                            \
    a3_.u[1] = pk2(x0_[2]*y0_[2], x0_[3]*y0_[3]);                            \
    a3_.u[2] = pk2(x1_[0]*y1_[0], x1_[1]*y1_[1]);                            \
    a3_.u[3] = pk2(x1_[2]*y1_[2], x1_[3]*y1_[3]);                            \
    f32x4 d0_ = __builtin_amdgcn_mfma_f32_16x16x32_bf16(a0_.s, bw.s, z,0,0,0);\
    f32x4 d1_ = __builtin_amdgcn_mfma_f32_16x16x32_bf16(a1_.s, bw.s, z,0,0,0);\
    f32x4 d2_ = __builtin_amdgcn_mfma_f32_16x16x32_bf16(a2_.s, bw.s, z,0,0,0);\
    f32x4 d3_ = __builtin_amdgcn_mfma_f32_16x16x32_bf16(a3_.s, bw.s, z,0,0,0);\
    CUR[0].u[0]=pk2(d0_[0],d0_[1]); CUR[0].u[1]=pk2(d0_[2],d0_[3]);          \
    CUR[1].u[0]=pk2(d1_[0],d1_[1]); CUR[1].u[1]=pk2(d1_[2],d1_[3]);          \
    CUR[2].u[0]=pk2(d2_[0],d2_[1]); CUR[2].u[1]=pk2(d2_[2],d2_[3]);          \
    CUR[3].u[0]=pk2(d3_[0],d3_[1]); CUR[3].u[1]=pk2(d3_[2],d3_[3]);          \
} while (0)

// V: register-only hand-off (H D-fragments are V's B-fragments), 8x MFMA K=16
#define V_PHASE(CUR, PRV) do {                                               \
    f32x4 c0_ = MFMA16(awhi.s, CUR[0].s, z);                                 \
    f32x4 c1_ = MFMA16(awhi.s, CUR[1].s, z);                                 \
    f32x4 c2_ = MFMA16(awhi.s, CUR[2].s, z);                                 \
    f32x4 c3_ = MFMA16(awhi.s, CUR[3].s, z);                                 \
    c0_ = MFMA16(awlo.s, PRV[0].s, c0_);                                     \
    c1_ = MFMA16(awlo.s, PRV[1].s, c1_);                                     \
    c2_ = MFMA16(awlo.s, PRV[2].s, c2_);                                     \
    c3_ = MFMA16(awlo.s, PRV[3].s, c3_);                                     \
    _Pragma("unroll")                                                        \
    for (int i = 0; i < 4; ++i) {                                            \
        const float u1   = c0_[i];                                           \
        const float u2   = c1_[i];                                           \
        const float m11  = u1 * u1;                                          \
        const float m22  = u2 * u2;                                          \
        const float m12  = u1 * u2;                                          \
        const float esum = c2_[i] * c2;      /* e11+e22 */                   \
        const float e12  = c3_[i] * c2;                                      \
        const float A_ = fmaf(2.f, m12, K1);                                 \
        const float B_ = fmaf(2.f, e12 - m12, K2);                           \
        const float C_ = m11 + m22 + K1;                                     \
        const float D_ = esum - (m11 + m22) + K2;                            \
        lsum = fmaf(A_ * B_, __builtin_amdgcn_rcpf(C_ * D_), lsum);          \
    }                                                                        \
} while (0)

__global__ __launch_bounds__(BLOCK, 4)
void ssim_tiled(const float* __restrict__ pred,
                const float* __restrict__ targ,
                float* __restrict__ accum, WB wb) {
    // triple-buffered raw f32 staging: 3 bufs x {x,y} x 1280 floats = 30,720 B
    __shared__ __align__(16) float s_buf[3][2][1280];

    const int tid = threadIdx.x;
    const int bx    = blockIdx.x;
    const int plane = bx >> 5;
    const int rem   = bx & 31;
    const int tx    = rem >> 2;
    const int ry    = rem & 3;
    const int C0    = tx * 64;
    const int R0    = ry * 128;

    const float* P = pred + (size_t)plane * (IMG * IMG);
    const float* T = targ + (size_t)plane * (IMG * IMG);
    const float* zp = accum + NACC;      // 16B zero page (memset by host code)

    const int w    = tid >> 6;
    const int lane = tid & 63;
    const int l15  = lane & 15;
    const int quad = lane >> 4;

    // ---- staging (write) side: lane -> slot -> rotated global chunk ----
    const int sA = w * 80 + lane;
    const int rA = sA / 20, pA = sA % 20;
    const int cA = (pA + 7 * rA) % 20;
    const int colA = C0 - 8 + 4 * cA;
    const bool colokA = (colA >= 0) && (colA + 4 <= IMG);
    const int sB = w * 80 + 64 + lane;   // meaningful for lane<16
    const int rB = sB / 20, pB = sB % 20;
    const int cB = (pB + 7 * rB) % 20;
    const int colB = C0 - 8 + 4 * cB;
    const bool colokB = (colB >= 0) && (colB + 4 <= IMG);

    // step-0 source bases (row R0-5+r); may be OOB-by-address for bad rows —
    // never dereferenced (SRC* selects zp). step s adds s*8192 floats.
    const float* baseXA = P + ((size_t)(R0 - 5 + rA) << 9) + colA;
    const float* baseYA = T + ((size_t)(R0 - 5 + rA) << 9) + colA;
    const float* baseXB = P + ((size_t)(R0 - 5 + rB) << 9) + colB;
    const float* baseYB = T + ((size_t)(R0 - 5 + rB) << 9) + colB;

    // ---- H (read) side: chunks c1,c1+1 of row l15, rotated positions ----
    const int c1 = 4 * w + 2 * quad;
    const int p1 = (c1 + 13 * l15) % 20;
    const int p2 = (c1 + 1 + 13 * l15) % 20;
    const int offX1 = (l15 * 20 + p1) * 4;
    const int offX2 = (l15 * 20 + p2) * 4;

    const float c2 = wb.c2, K1 = wb.k1, K2 = wb.k2;
    const f32x4 z = {0.f, 0.f, 0.f, 0.f};
    float lsum = 0.f;

    // ---- prologue: 2 step-tiles of DMA in flight, weights under latency ----
    ISSUE(0);
    ISSUE(1);

    // weight fragments in registers (verified R4..R17):
    // T[i] = ((i&31)<=10) ? b[i&31] : 0 ; pairT[i] = (T[i], T[(i+1)&63]).
    // bw   (H, K=32 B-op): word t = pairT[(8*quad - l15 - 3 + 2t)&63]
    // awlo (V, K=16 A-op): word t = pairT[(4*quad - l15      + 2t)&63]
    // awhi (V, K=16 A-op): word t = pairT[(4*quad - l15 + 16 + 2t)&63]
    FR bw; FR2 awlo, awhi;
    {
        const int ti = lane & 31;
        int tv = 0;
#pragma unroll
        for (int k = 0; k < 11; ++k) tv = (ti == k) ? (int)wb.b[k] : tv;
        const int tnext = __shfl(tv, (lane + 1) & 63);
        const int pairT = (tv & 0xffff) | (tnext << 16);
        const int base_b = 8 * quad - l15 - 3;
        const int baseL  = 4 * quad - l15;
        const int baseH  = 4 * quad - l15 + 16;
#pragma unroll
        for (int t = 0; t < 4; ++t)
            bw.u[t] = (unsigned int)__shfl(pairT, (base_b + 2 * t) & 63);
#pragma unroll
        for (int t = 0; t < 2; ++t) {
            awlo.u[t] = (unsigned int)__shfl(pairT, (baseL + 2 * t) & 63);
            awhi.u[t] = (unsigned int)__shfl(pairT, (baseH + 2 * t) & 63);
        }
    }

    WAITSYNC(4);                   // step-0 DMA landed (step-1 still flying)

    FR2 vbE[4], vbO[4];            // H fragments, even/odd steps

    // STEP(s): issue DMA(s+2) -> buf[(s+2)%3] (last read at s-1, safe);
    // H reads buf[s%3]; end: vmcnt(4) keeps DMA(s+2) flying, drains DMA(s+1).
    ISSUE(2);  H_PHASE(vbE, 0);                        WAITSYNC(4);
    ISSUE(3);  H_PHASE(vbO, 1);  V_PHASE(vbO, vbE);    WAITSYNC(4);
    ISSUE(4);  H_PHASE(vbE, 2);  V_PHASE(vbE, vbO);    WAITSYNC(4);
    ISSUE(5);  H_PHASE(vbO, 3);  V_PHASE(vbO, vbE);    WAITSYNC(4);
    ISSUE(6);  H_PHASE(vbE, 4);  V_PHASE(vbE, vbO);    WAITSYNC(4);
    ISSUE(7);  H_PHASE(vbO, 5);  V_PHASE(vbO, vbE);    WAITSYNC(4);
    ISSUE(8);  H_PHASE(vbE, 6);  V_PHASE(vbE, vbO);    WAITSYNC(4);
               H_PHASE(vbO, 7);  V_PHASE(vbO, vbE);    WAITSYNC(0);
               H_PHASE(vbE, 8);  V_PHASE(vbE, vbO);

#pragma unroll
    for (int off = 32; off > 0; off >>= 1) lsum += __shfl_down(lsum, off, 64);
    if (lane == 0) atomicAdd(&accum[(bx * 4 + w) & (NACC - 1)], lsum);
}

__global__ void ssim_finalize(const float* __restrict__ accum, float* __restrict__ out) {
    const int l = threadIdx.x;
    float v = accum[l] + accum[l + 64];
#pragma unroll
    for (int off = 32; off > 0; off >>= 1) v += __shfl_down(v, off, 64);
    if (l == 0) out[0] = 1.0f - v * (1.0f / N_TOTAL);
}

extern "C" void kernel_launch(void* const* d_in, const int* in_sizes, int n_in,
                              void* d_out, int out_size, void* d_ws, size_t ws_size,
                              hipStream_t stream) {
    const float* pred = (const float*)d_in[0];
    const float* targ = (const float*)d_in[1];
    float* out = (float*)d_out;
    float* ws  = (float*)d_ws;

    WB wb;
    {
        double gg[11], sum = 0.0;
        for (int k = 0; k < 11; ++k) {
            const double d = (double)(k - 5);
            gg[k] = exp(-d * d / 4.5);
            sum += gg[k];
        }
        double sbf = 0.0;
        for (int k = 0; k < 11; ++k) {
            union { float f; unsigned int u; } cv;
            cv.f = (float)(gg[k] / sum);
            const unsigned int r = (cv.u + 0x7fffu + ((cv.u >> 16) & 1u)) >> 16;
            wb.b[k] = (unsigned short)r;
            union { float f; unsigned int u; } bk;
            bk.u = r << 16;
            sbf += (double)bk.f;
        }
        const double s2 = sbf * sbf;       // acc = s2 * true value
        wb.c2 = (float)s2;
        wb.k1 = (float)(0.0001 * s2 * s2); // C1 in acc^2 units
        wb.k2 = (float)(0.0009 * s2 * s2); // C2 in acc^2 units
    }

    // accum[0..NACC) = partial sums; accum[NACC..NACC+4) = DMA zero page
    hipMemsetAsync(ws, 0, (NACC + 4) * sizeof(float), stream);
    ssim_tiled<<<NBLOCKS, BLOCK, 0, stream>>>(pred, targ, ws, wb);
    ssim_finalize<<<1, 64, 0, stream>>>(ws, out);
}